// Round 16
// baseline (334.411 us; speedup 1.0000x reference)
//
#include <hip/hip_runtime.h>
#include <cstdint>
#include <cstddef>

#define TAU_D 2.053748910631823
#define M_DIM 8192
#define N_DIM 4096
#define K_DIM 4096
#define NT32  (K_DIM / 32)     // 128 K-steps of BK=32

typedef float f32x4  __attribute__((ext_vector_type(4)));
typedef short bf16x8 __attribute__((ext_vector_type(8)));

typedef __attribute__((address_space(1))) void gvoid_t;
typedef __attribute__((address_space(3))) void lvoid_t;

__device__ __forceinline__ void gload_lds16(const void* g, void* l) {
    __builtin_amdgcn_global_load_lds((const gvoid_t*)g, (lvoid_t*)l, 16, 0, 0);
}

__device__ __forceinline__ unsigned int pack2bf(float lo, float hi) {
    unsigned int ul = __float_as_uint(lo);
    unsigned int uh = __float_as_uint(hi);
    ul = (ul + 0x7FFFu + ((ul >> 16) & 1u)) >> 16;
    uh = (uh + 0x7FFFu + ((uh >> 16) & 1u)) >> 16;
    return ul | (uh << 16);
}

// fp32 -> bf16 (RNE), vectorized: 16B in / 8B out per thread per iter.
__global__ void cvt_f32_to_bf16(const float4* __restrict__ in,
                                uint2* __restrict__ out, int n4) {
    int i = blockIdx.x * blockDim.x + threadIdx.x;
    const int stride = gridDim.x * blockDim.x;
    for (; i < n4; i += stride) {
        float4 a = in[i];
        uint2 o;
        o.x = pack2bf(a.x, a.y);
        o.y = pack2bf(a.z, a.w);
        out[i] = o;
    }
}

// Raw barrier + compiler-only memory fence.
#define BAR() do { __builtin_amdgcn_s_barrier(); \
                   asm volatile("" ::: "memory"); } while (0)

// ============================================================================
// FAT-SPAN DESTAGGER: reads AND their MFMA between the SAME barrier pair.
// Diagnosis (r15 pipe accounting): iter = LDS-service(4600cy) + MFMA(4966cy)
// SERIALIZED because barrier-locked phases put reads and MFMA in different
// windows -> convoy. This kernel: one span per BK=32 K-step, ONE barrier:
//   span T: [reads B4+Aq0 | stage(T+2) | MFMA q0 | reads Aq1 | MFMA q1 |
//            vmcnt(4) | BAR]
// Waves serviced first start MFMA while stragglers' reads are in the LDS
// queue -> cross-wave LDS||MFMA overlap; setprio(1) favors MFMA-phase waves
// (real role-split -> T5 applies).
// Geometry = r7 (verified absmax 2.0): 256x256 tile, 8 waves (2Mx4N),
// 3 LDS buffers x 32KB (96KB), slot-rotation swizzle phys=(lq+(lr>>1))&3,
// staging pre-rotated global column, linear LDS dest.
// Ledger (hand-checked): stage at span T targets buf[(T+2)%3] -- never the
// buffer read this span or next. vmcnt(4) at span end: outstanding =
// [T-1's 4][T's 4]; forces T+1's data (read next span), 4 fly across BAR.
// WAR: buf[(T+2)%3] last read span T-1; staging wave passed BAR(T-1) which
// all waves reach only after their reads' consuming MFMA (lgkm) + >=400cy
// gload write latency (same argument validated r7/r14/r15).
// Tail: T=NT-2 vmcnt(0); T=NT-1 none. XCD map verified r6 (FETCH 208MB).
// Epilogue bit-exact fp32 mask (verified r3-r15).
// ============================================================================
__global__ __launch_bounds__(512, 2) void gemm_masked8(
    const unsigned short* __restrict__ Ab,   // x bf16 [M][K]
    const unsigned short* __restrict__ Bb,   // W bf16 [N][K]
    const float* __restrict__ X,             // x fp32 (mask)
    const float* __restrict__ Wt,            // W fp32 (mask)
    const float* __restrict__ bias,
    float* __restrict__ out)
{
    __shared__ __align__(16) char lds[98304];   // 3 x (A 16KB + B 16KB)

    const int tid  = threadIdx.x;
    const int wave = tid >> 6;
    const int lane = tid & 63;
    const int lr = lane & 15;
    const int lq = lane >> 4;
    const int wm = wave >> 2;    // 0..1 : row half (128 rows)
    const int wn = wave & 3;     // 0..3 : 64-col slice

    // Concurrency-aware XCD cluster map (verified r6).
    const int flat = blockIdx.x;
    const int xcd  = flat & 7;
    const int s    = flat >> 3;            // 0..63
    const int rnd  = s >> 5;               // 0..1
    const int jj   = s & 31;               // 0..31
    const int trow = rnd * 16 + ((xcd >> 2) << 3) + (jj >> 2);   // 0..31
    const int tcol = ((xcd & 3) << 2) + (jj & 3);                // 0..15
    const int rowBase = trow * 256;
    const int colBase = tcol * 256;

    f32x4 acc[8][4];
    #pragma unroll
    for (int i = 0; i < 8; ++i)
        #pragma unroll
        for (int n = 0; n < 4; ++n)
            acc[i][n] = (f32x4){0.f, 0.f, 0.f, 0.f};

    // ---- staging (r7-verified): linear LDS dest; global col pre-rotated ---
    // gload pass i: row = i*128 + (tid>>2), phys slot = tid&3;
    // logical = ((tid&3) - ((tid>>3)&3)) & 3   (phys = (log + (row>>1))&3).
    const int srow = tid >> 2;                                   // 0..127
    const int slog = ((tid & 3) - ((tid >> 3) & 3)) & 3;
    const unsigned short* aSrc =
        Ab + (size_t)(rowBase + srow) * K_DIM + slog * 8;
    const unsigned short* bSrc =
        Bb + (size_t)(colBase + srow) * K_DIM + slog * 8;

    auto stageK = [&](int kst, unsigned bo) {   // stage full K-step (A+B)
        #pragma unroll
        for (int i = 0; i < 2; ++i)
            gload_lds16(aSrc + (size_t)i * 128 * K_DIM + kst * 32,
                        lds + bo + i * 8192 + wave * 1024);
        #pragma unroll
        for (int i = 0; i < 2; ++i)
            gload_lds16(bSrc + (size_t)i * 128 * K_DIM + kst * 32,
                        lds + bo + 16384 + i * 8192 + wave * 1024);
    };

    // ---- ds_read offsets (r7-verified swizzle) ----
    // byte = row*64 + ((lq + (lr>>1)) & 3)*16 ; row = whalf + frag*16 + lr.
    const unsigned skrot = (unsigned)((lq + (lr >> 1)) & 3) * 16;
    const unsigned offA0 = (unsigned)(wm * 128 + lr) * 64 + skrot;   // + m*1024
    const unsigned offB0 = 16384u + (unsigned)(wn * 64 + lr) * 64 + skrot;

    // ---- prologue: stage K-steps 0 and 1; vmcnt(4); publication BAR ----
    stageK(0, 0);
    stageK(1, 32768);
    asm volatile("s_waitcnt vmcnt(4)" ::: "memory");   // K0 landed; K1 flying
    BAR();

    unsigned b0 = 0, b1 = 32768, b2 = 65536;   // read T / T+1 / stage T+2

    for (int T = 0; T < NT32; ++T) {
        const char* L = lds + b0;

        bf16x8 bF[4], aq[4];

        // ---- reads: B all 4 n-frags + A q0; then stage T+2 (early issue) --
        #pragma unroll
        for (int n = 0; n < 4; ++n)
            bF[n] = *(const bf16x8*)(L + offB0 + n * 1024);
        #pragma unroll
        for (int m = 0; m < 4; ++m)
            aq[m] = *(const bf16x8*)(L + offA0 + m * 1024);
        if (T + 2 < NT32) stageK(T + 2, b2);

        // ---- MFMA q0 (16) -- starts when own reads land; other waves'
        //      reads stream through the LDS pipe underneath ----
        __builtin_amdgcn_s_setprio(1);
        #pragma unroll
        for (int m = 0; m < 4; ++m)
            #pragma unroll
            for (int n = 0; n < 4; ++n)
                acc[m][n] = __builtin_amdgcn_mfma_f32_16x16x32_bf16(
                    aq[m], bF[n], acc[m][n], 0, 0, 0);
        __builtin_amdgcn_s_setprio(0);

        // ---- reads A q1; MFMA q1 (16) ----
        #pragma unroll
        for (int m = 0; m < 4; ++m)
            aq[m] = *(const bf16x8*)(L + offA0 + (4 + m) * 1024);
        __builtin_amdgcn_s_setprio(1);
        #pragma unroll
        for (int m = 0; m < 4; ++m)
            #pragma unroll
            for (int n = 0; n < 4; ++n)
                acc[4 + m][n] = __builtin_amdgcn_mfma_f32_16x16x32_bf16(
                    aq[m], bF[n], acc[4 + m][n], 0, 0, 0);
        __builtin_amdgcn_s_setprio(0);

        // ---- span end: counted vmcnt (publication of T+1), ONE barrier ----
        if (T + 2 < NT32) {
            asm volatile("s_waitcnt vmcnt(4)" ::: "memory");
        } else if (T + 1 < NT32) {
            asm volatile("s_waitcnt vmcnt(0)" ::: "memory");
        }
        BAR();

        unsigned t = b0; b0 = b1; b1 = b2; b2 = t;
    }

    // ---- epilogue: bit-exact fp32 mask + bias + store (verified r3-r15) ---
    __syncthreads();
    float* x0s = (float*)(lds);            // [256][16] f32, 16KB
    float* w0s = (float*)(lds + 16384);    // [256][16] f32
    #pragma unroll
    for (int i = 0; i < 2; ++i) {
        int idx = tid + i * 512;           // 1024 float4 slots
        int r = idx >> 2, qq = (idx & 3) << 2;
        *(f32x4*)(x0s + r * 16 + qq) =
            *(const f32x4*)(X + (size_t)(rowBase + r) * K_DIM + qq);
        *(f32x4*)(w0s + r * 16 + qq) =
            *(const f32x4*)(Wt + (size_t)(colBase + r) * K_DIM + qq);
    }
    __syncthreads();

    const float TAU32 = (float)TAU_D;

    // n in adjacent pairs: both 64B halves of each 128B output line stored
    // back-to-back (write-amplification fix, verified r6-r15).
    #pragma unroll
    for (int np = 0; np < 4; np += 2) {
        float wv[2][16];
        float bv[2];
        #pragma unroll
        for (int e = 0; e < 2; ++e) {
            const int c = wn * 64 + (np + e) * 16 + lr;
            #pragma unroll
            for (int q = 0; q < 4; ++q)
                *(f32x4*)&wv[e][q * 4] = *(const f32x4*)(w0s + c * 16 + q * 4);
            bv[e] = bias[colBase + c];
        }
        #pragma unroll
        for (int mi = 0; mi < 8; ++mi) {
            #pragma unroll
            for (int jr = 0; jr < 4; ++jr) {
                const int rw = wm * 128 + mi * 16 + lq * 4 + jr;
                float xv[16];
                #pragma unroll
                for (int q = 0; q < 4; ++q)
                    *(f32x4*)&xv[q * 4] = *(const f32x4*)(x0s + rw * 16 + q * 4);
                const size_t orow = (size_t)(rowBase + rw) * N_DIM + colBase;
                #pragma unroll
                for (int e = 0; e < 2; ++e) {
                    const int n = np + e;
                    // Replicate BLAS sgemm: single-acc fma chain, k ascending.
                    float y1 = 0.f, s2 = 0.f;
                    #pragma unroll
                    for (int k = 0; k < 16; ++k) {
                        float xk = xv[k], wk = wv[e][k];
                        float xx = xk * xk, ww = wk * wk;
                        y1 = fmaf(xk, wk, y1);
                        s2 = fmaf(xx, ww, s2);
                    }
                    float t = fabsf(y1) / sqrtf(s2 * 0.0625f);
                    float v = (t < TAU32) ? 0.0f : (acc[mi][n][jr] + bv[e]);
                    out[orow + wn * 64 + n * 16 + lr] = v;
                }
            }
        }
    }
}

// ============================================================================
// Fallback (no workspace): round-3 verified 128x128 kernel, reg-staged cvt.
// ============================================================================
__global__ __launch_bounds__(256, 2) void gemm_masked_fb(
    const float* __restrict__ X, const float* __restrict__ Wt,
    const float* __restrict__ bias, float* __restrict__ out)
{
    __shared__ __align__(16) unsigned short As[128 * 32];
    __shared__ __align__(16) unsigned short Bs[128 * 32];

    const int tid  = threadIdx.x;
    const int wave = tid >> 6;
    const int lane = tid & 63;
    const int rowBase = blockIdx.y * 128;
    const int colBase = blockIdx.x * 128;
    const int wr = wave >> 1;
    const int wc = wave & 1;
    const int lr = lane & 15;
    const int lq = lane >> 4;

    f32x4 acc[4][4];
    #pragma unroll
    for (int m = 0; m < 4; ++m)
        #pragma unroll
        for (int n = 0; n < 4; ++n)
            acc[m][n] = (f32x4){0.f, 0.f, 0.f, 0.f};

    const int srow = tid >> 2;
    const int scol = (tid & 3) * 8;
    const float* afp = X  + (size_t)(rowBase + srow) * K_DIM + scol;
    const float* bfp = Wt + (size_t)(colBase + srow) * K_DIM + scol;

    for (int kt = 0; kt < K_DIM; kt += 32) {
        #pragma unroll
        for (int issue = 0; issue < 2; ++issue) {
            const float* sa = afp + (size_t)issue * 64 * K_DIM;
            const float* sb = bfp + (size_t)issue * 64 * K_DIM;
            float4 a0 = *(const float4*)(sa);
            float4 a1 = *(const float4*)(sa + 4);
            float4 b0 = *(const float4*)(sb);
            float4 b1 = *(const float4*)(sb + 4);
            uint4 pa, pb;
            pa.x = pack2bf(a0.x, a0.y); pa.y = pack2bf(a0.z, a0.w);
            pa.z = pack2bf(a1.x, a1.y); pa.w = pack2bf(a1.z, a1.w);
            pb.x = pack2bf(b0.x, b0.y); pb.y = pack2bf(b0.z, b0.w);
            pb.z = pack2bf(b1.x, b1.y); pb.w = pack2bf(b1.z, b1.w);
            *(uint4*)((char*)As + issue * 4096 + tid * 16) = pa;
            *(uint4*)((char*)Bs + issue * 4096 + tid * 16) = pb;
        }
        afp += 32; bfp += 32;
        __syncthreads();

        bf16x8 af[4], bq[4];
        #pragma unroll
        for (int m = 0; m < 4; ++m)
            af[m] = *(const bf16x8*)(As + (wr * 64 + m * 16 + lr) * 32 + lq * 8);
        #pragma unroll
        for (int n = 0; n < 4; ++n)
            bq[n] = *(const bf16x8*)(Bs + (wc * 64 + n * 16 + lr) * 32 + lq * 8);
        #pragma unroll
        for (int m = 0; m < 4; ++m)
            #pragma unroll
            for (int n = 0; n < 4; ++n)
                acc[m][n] = __builtin_amdgcn_mfma_f32_16x16x32_bf16(
                    af[m], bq[n], acc[m][n], 0, 0, 0);
        __syncthreads();
    }

    float* x0s = (float*)As;
    float* w0s = (float*)Bs;
    #pragma unroll
    for (int i = 0; i < 2; ++i) {
        int idx = tid + i * 256;
        int r = idx >> 2, q = (idx & 3) * 4;
        *(float4*)(x0s + r * 16 + q) =
            *(const float4*)(X + (size_t)(rowBase + r) * K_DIM + q);
        *(float4*)(w0s + r * 16 + q) =
            *(const float4*)(Wt + (size_t)(colBase + r) * K_DIM + q);
    }
    __syncthreads();

    const float TAU32 = (float)TAU_D;
    float wv[4][16];
    float bv[4];
    #pragma unroll
    for (int n = 0; n < 4; ++n) {
        int c = wc * 64 + n * 16 + lr;
        #pragma unroll
        for (int q = 0; q < 4; ++q)
            *(f32x4*)&wv[n][q * 4] = *(const f32x4*)(w0s + c * 16 + q * 4);
        bv[n] = bias[colBase + c];
    }

    #pragma unroll
    for (int m = 0; m < 4; ++m) {
        #pragma unroll
        for (int j = 0; j < 4; ++j) {
            const int r = wr * 64 + m * 16 + lq * 4 + j;
            float xv[16];
            #pragma unroll
            for (int q = 0; q < 4; ++q)
                *(f32x4*)&xv[q * 4] = *(const f32x4*)(x0s + r * 16 + q * 4);
            const size_t orow = (size_t)(rowBase + r) * N_DIM + colBase;
            #pragma unroll
            for (int n = 0; n < 4; ++n) {
                float y1 = 0.f, s2 = 0.f;
                #pragma unroll
                for (int k = 0; k < 16; ++k) {
                    float xk = xv[k];
                    float wk = wv[n][k];
                    float xx = xk * xk;
                    float ww = wk * wk;
                    y1 = fmaf(xk, wk, y1);
                    s2 = fmaf(xx, ww, s2);
                }
                float t = fabsf(y1) / sqrtf(s2 * 0.0625f);
                float v = (t < TAU32) ? 0.0f : (acc[m][n][j] + bv[n]);
                out[orow + wc * 64 + n * 16 + lr] = v;
            }
        }
    }
}

extern "C" void kernel_launch(void* const* d_in, const int* in_sizes, int n_in,
                              void* d_out, int out_size, void* d_ws, size_t ws_size,
                              hipStream_t stream) {
    const float* x    = (const float*)d_in[0];
    const float* W    = (const float*)d_in[1];
    const float* bias = (const float*)d_in[2];
    float* out = (float*)d_out;

    const size_t needA = (size_t)M_DIM * K_DIM * 2;   // 64 MB
    const size_t needB = (size_t)N_DIM * K_DIM * 2;   // 32 MB

    if (ws_size >= needA + needB) {
        unsigned short* xb = (unsigned short*)d_ws;
        unsigned short* wb = (unsigned short*)((char*)d_ws + needA);
        cvt_f32_to_bf16<<<2048, 256, 0, stream>>>(
            (const float4*)x, (uint2*)xb, (M_DIM * K_DIM) / 4);
        cvt_f32_to_bf16<<<2048, 256, 0, stream>>>(
            (const float4*)W, (uint2*)wb, (N_DIM * K_DIM) / 4);
        dim3 grid((M_DIM / 256) * (N_DIM / 256));     // 512 blocks, 1-D
        gemm_masked8<<<grid, 512, 0, stream>>>(xb, wb, x, W, bias, out);
    } else {
        dim3 grid(N_DIM / 128, M_DIM / 128);
        gemm_masked_fb<<<grid, 256, 0, stream>>>(x, W, bias, out);
    }
}